// Round 1
// baseline (40926.947 us; speedup 1.0000x reference)
//
#include <hip/hip_runtime.h>
#include <hip/hip_bf16.h>

// FFJORD: 3 bijectors, each integrates dz/dt = MLP(t, z, cond) with 8 fixed
// DOPRI5 steps. MLP: [z(4), cond(4), t(1)] -> 128 -> 128 -> 4, tanh,tanh,linear.
//
// Design (R0, fp32 baseline):
//  - thread = batch element; h1[128] lives in VGPRs (all h1/ks indices compile-time)
//  - weights are wave-uniform -> compiler scalarizes to s_load (co-issues with VALU)
//  - FSAL: stage-7 input IS the step output and stage-7 k is next step's k1
//    (bitwise identical to the reference's recomputation) -> 144 evals not 168
//  - fast tanh: 1 - 2*rcp(exp(2x)+1) via native v_exp_f32 / v_rcp_f32

#define NBIJ 3
#define HD   128
#define DD   4
#define CDIM 4
#define DIN  9
#define JC   16
#define NSTEP 8

// Butcher tableau (rows 1..6; row 6 == 5th-order b weights). Row-major, fp32.
__device__ static const float AC[7][6] = {
    {0.f, 0.f, 0.f, 0.f, 0.f, 0.f},
    {0.2f, 0.f, 0.f, 0.f, 0.f, 0.f},
    {0.075f, 0.225f, 0.f, 0.f, 0.f, 0.f},
    {(float)(44.0/45.0), (float)(-56.0/15.0), (float)(32.0/9.0), 0.f, 0.f, 0.f},
    {(float)(19372.0/6561.0), (float)(-25360.0/2187.0), (float)(64448.0/6561.0),
     (float)(-212.0/729.0), 0.f, 0.f},
    {(float)(9017.0/3168.0), (float)(-355.0/33.0), (float)(46732.0/5247.0),
     (float)(49.0/176.0), (float)(-5103.0/18656.0), 0.f},
    {(float)(35.0/384.0), 0.0f, (float)(500.0/1113.0), (float)(125.0/192.0),
     (float)(-2187.0/6784.0), (float)(11.0/84.0)},
};
__device__ static const float CNODE[7] = {
    0.0f, 0.2f, 0.3f, 0.8f, (float)(8.0/9.0), 1.0f, 1.0f
};

__device__ __forceinline__ float fast_tanh(float x) {
    x = fminf(9.0f, fmaxf(-9.0f, x));           // avoid inf/inf
    float e = __expf(2.0f * x);                 // native v_exp_f32 path
    float r = __builtin_amdgcn_rcpf(e + 1.0f);  // approx rcp, ~1 ulp
    return fmaf(-2.0f, r, 1.0f);                // (e-1)/(e+1)
}

// One MLP evaluation: kout = W3^T tanh(W2^T tanh(W1^T [y,c,t] + b1) + b2) + b3
__device__ __forceinline__ void mlp_eval(
    const float* __restrict__ w1, const float* __restrict__ b1,
    const float* __restrict__ w2, const float* __restrict__ b2,
    const float* __restrict__ w3, const float* __restrict__ b3,
    const float y[DD], const float c[CDIM], float t, float kout[DD])
{
    float in9[DIN] = {y[0], y[1], y[2], y[3], c[0], c[1], c[2], c[3], t};

    // Layer 1: k-outer so each k reads a contiguous 128-float W1 row (s_load friendly)
    float h1[HD];
    #pragma unroll
    for (int j = 0; j < HD; ++j) h1[j] = b1[j];
    #pragma unroll
    for (int k = 0; k < DIN; ++k) {
        float v = in9[k];
        const float* wrow = w1 + k * HD;
        #pragma unroll
        for (int j = 0; j < HD; ++j) h1[j] = fmaf(v, wrow[j], h1[j]);
    }
    #pragma unroll
    for (int j = 0; j < HD; ++j) h1[j] = fast_tanh(h1[j]);

    // Layers 2+3 fused; JC-wide output chunks (runtime jc loop keeps code small,
    // all register array indices remain compile-time).
    float o0 = b3[0], o1 = b3[1], o2 = b3[2], o3 = b3[3];
    for (int jc = 0; jc < HD / JC; ++jc) {
        const int jbase = jc * JC;
        float acc[JC];
        #pragma unroll
        for (int jj = 0; jj < JC; ++jj) acc[jj] = b2[jbase + jj];
        #pragma unroll
        for (int k = 0; k < HD; ++k) {
            float hk = h1[k];
            const float* wrow = w2 + k * HD + jbase;
            #pragma unroll
            for (int jj = 0; jj < JC; ++jj)
                acc[jj] = fmaf(hk, wrow[jj], acc[jj]);
        }
        #pragma unroll
        for (int jj = 0; jj < JC; ++jj) {
            float h2 = fast_tanh(acc[jj]);
            const float* w3r = w3 + (jbase + jj) * DD;
            o0 = fmaf(h2, w3r[0], o0);
            o1 = fmaf(h2, w3r[1], o1);
            o2 = fmaf(h2, w3r[2], o2);
            o3 = fmaf(h2, w3r[3], o3);
        }
    }
    kout[0] = o0; kout[1] = o1; kout[2] = o2; kout[3] = o3;
}

extern "C" __global__ void __launch_bounds__(256, 2) ffjord_kernel(
    const float* __restrict__ X, const float* __restrict__ CIN,
    const float* __restrict__ W1, const float* __restrict__ B1,
    const float* __restrict__ W2, const float* __restrict__ B2,
    const float* __restrict__ W3, const float* __restrict__ B3,
    float* __restrict__ OUT, int btot)
{
    int i = blockIdx.x * blockDim.x + threadIdx.x;
    if (i >= btot) return;

    float4 xv = reinterpret_cast<const float4*>(X)[i];
    float4 cv = reinterpret_cast<const float4*>(CIN)[i];
    float z[DD] = {xv.x, xv.y, xv.z, xv.w};
    float c[CDIM] = {cv.x, cv.y, cv.z, cv.w};
    const float dt = 0.125f;

    for (int bij = 0; bij < NBIJ; ++bij) {
        const float* w1 = W1 + bij * DIN * HD;
        const float* b1 = B1 + bij * HD;
        const float* w2 = W2 + bij * HD * HD;
        const float* b2 = B2 + bij * HD;
        const float* w3 = W3 + bij * HD * DD;
        const float* b3 = B3 + bij * DD;

        float ks[7][DD];
        mlp_eval(w1, b1, w2, b2, w3, b3, z, c, 0.0f, ks[0]);  // k1 of step 0

        for (int s = 0; s < NSTEP; ++s) {
            float t0 = s * dt;
            bool last = (s == NSTEP - 1);

            for (int st = 1; st <= 6; ++st) {
                // y = z + dt * sum_{j<st} A[st][j] * ks[j]
                float y[DD];
                #pragma unroll
                for (int d = 0; d < DD; ++d) y[d] = z[d];
                #pragma unroll
                for (int j = 0; j < 6; ++j) {
                    if (j < st) {
                        float a = dt * AC[st][j];
                        #pragma unroll
                        for (int d = 0; d < DD; ++d)
                            y[d] = fmaf(a, ks[j][d], y[d]);
                    }
                }
                if (st == 6) {
                    // row 6 == b: y IS the step output (FSAL)
                    #pragma unroll
                    for (int d = 0; d < DD; ++d) z[d] = y[d];
                    if (last) break;  // k7 only needed as next step's k1
                }
                float tt = fmaf(CNODE[st], dt, t0);
                float kt[DD];
                mlp_eval(w1, b1, w2, b2, w3, b3, y, c, tt, kt);
                // scatter kt -> ks[st] with compile-time indices (keep ks in VGPRs)
                #pragma unroll
                for (int j2 = 1; j2 <= 5; ++j2) {
                    if (j2 == st) {
                        #pragma unroll
                        for (int d = 0; d < DD; ++d) ks[j2][d] = kt[d];
                    }
                }
                if (st == 6) {  // FSAL: k7 == next step's k1 (bitwise)
                    #pragma unroll
                    for (int d = 0; d < DD; ++d) ks[0][d] = kt[d];
                }
            }
        }
    }

    reinterpret_cast<float4*>(OUT)[i] =
        make_float4(z[0], z[1], z[2], z[3]);
}

extern "C" void kernel_launch(void* const* d_in, const int* in_sizes, int n_in,
                              void* d_out, int out_size, void* d_ws, size_t ws_size,
                              hipStream_t stream) {
    const float* X  = (const float*)d_in[0];
    const float* CI = (const float*)d_in[1];
    const float* W1 = (const float*)d_in[2];
    const float* B1 = (const float*)d_in[3];
    const float* W2 = (const float*)d_in[4];
    const float* B2 = (const float*)d_in[5];
    const float* W3 = (const float*)d_in[6];
    const float* B3 = (const float*)d_in[7];
    float* OUT = (float*)d_out;

    int btot = in_sizes[0] / DD;  // 262144
    int block = 256;
    int grid = (btot + block - 1) / block;
    ffjord_kernel<<<grid, block, 0, stream>>>(X, CI, W1, B1, W2, B2, W3, B3, OUT, btot);
}

// Round 2
// 4046.771 us; speedup vs baseline: 10.1135x; 10.1135x over previous
//
#include <hip/hip_runtime.h>
#include <hip/hip_bf16.h>

// FFJORD: 3 bijectors x 8 DOPRI5 steps (FSAL -> 6 MLP evals/step + 1 initial).
// MLP: [z(4), cond(4), t(1)] ->128 ->128 ->4, tanh,tanh,linear.
//
// R1 design: transposed MFMA scheme. All activations feature-major (F^T), so
// batch index = lane&15 in both B-fragments and C-fragments:
//   L: H^T = W^T @ X^T via mfma_f32_16x16x32_bf16(A=W^T frags, B=act frags).
// - wave owns 16 batch rows; block = 4 waves = 64 rows; grid = 4096.
// - W2 A-frags persistent in 128 VGPRs (48 evals/bijector amortize the load).
// - W1/W3 A-frags + biases staged in LDS (tiny traffic).
// - h1/h2 bounce via 4KB/wave LDS buffer, XOR-swizzled on BOTH sides
//   (byte ^ (r&7)<<4) -> bank conflicts at the BW floor.
// - RK state z/ks in C-frag layout: only group-0 lanes (lane<16) meaningful.
//   ks kept in LDS (16B/lane/stage) so the stage loop stays runtime (small code).
// - A/B k-mapping (k = (lane>>4)*8 + e) used consistently on both operands, so
//   any true-vs-assumed k-permutation cancels in the dot product.

#define NBIJ 3
#define NSTEP 8

typedef float f32x4 __attribute__((ext_vector_type(4)));
typedef short short8 __attribute__((ext_vector_type(8)));

__device__ static const float AC[7][6] = {
    {0.f, 0.f, 0.f, 0.f, 0.f, 0.f},
    {0.2f, 0.f, 0.f, 0.f, 0.f, 0.f},
    {0.075f, 0.225f, 0.f, 0.f, 0.f, 0.f},
    {(float)(44.0/45.0), (float)(-56.0/15.0), (float)(32.0/9.0), 0.f, 0.f, 0.f},
    {(float)(19372.0/6561.0), (float)(-25360.0/2187.0), (float)(64448.0/6561.0),
     (float)(-212.0/729.0), 0.f, 0.f},
    {(float)(9017.0/3168.0), (float)(-355.0/33.0), (float)(46732.0/5247.0),
     (float)(49.0/176.0), (float)(-5103.0/18656.0), 0.f},
    {(float)(35.0/384.0), 0.0f, (float)(500.0/1113.0), (float)(125.0/192.0),
     (float)(-2187.0/6784.0), (float)(11.0/84.0)},
};
__device__ static const float CN[7] = {
    0.0f, 0.2f, 0.3f, 0.8f, (float)(8.0/9.0), 1.0f, 1.0f
};

union U4S8 { unsigned u[4]; short8 s; };

__device__ __forceinline__ unsigned short bf16_bits(float a) {
    union { __hip_bfloat16 h; unsigned short u; } v;
    v.h = __float2bfloat16(a);   // RNE
    return v.u;
}
__device__ __forceinline__ unsigned pk_bf16(float a, float b) {
    return (unsigned)bf16_bits(a) | ((unsigned)bf16_bits(b) << 16);
}

__device__ __forceinline__ float fast_tanh(float x) {
    // 1 - 2/(e^{2x}+1); inf/0 arithmetic saturates correctly, no clamp needed
    float e = __expf(2.0f * x);
    float r = __builtin_amdgcn_rcpf(e + 1.0f);
    return fmaf(-2.0f, r, 1.0f);
}

struct SMem {
    alignas(16) short w1f[8][64][8];     // W1^T A-frags [jt][lane][e]  8 KB
    alignas(16) short w3f[4][64][8];     // W3^T A-frags [kt][lane][e]  4 KB
    alignas(16) float b1[128];
    alignas(16) float b2[128];
    alignas(16) float b3[16];            // zero-padded past 4
    alignas(16) unsigned hbuf[4][1024];  // per-wave h bounce, 4 KB each
    alignas(16) f32x4 ks[4][7][16];      // [wid][stage][r]  7 KB
};

__device__ __forceinline__ f32x4 mlp_eval(
    const f32x4 y, float t, unsigned c01, unsigned c23,
    const unsigned (&w2u)[8][4][4], SMem* sm, int wid, int lane)
{
    const int r = lane & 15, g = lane >> 4;
    const unsigned swz = (unsigned)((r & 7) << 4);
    char* hb = (char*)&sm->hbuf[wid][0];
    const unsigned base_w = (unsigned)(r * 256 + g * 8);
    const unsigned base_r = (unsigned)(r * 256 + g * 16);

    // ---- input B-frag: group0: [z0..z3, c0..c3]; group1: [t,0..]; g2,3: 0
    U4S8 inf;
    {
        unsigned zp01 = pk_bf16(y[0], y[1]);
        unsigned zp23 = pk_bf16(y[2], y[3]);
        unsigned tp   = pk_bf16(t, 0.0f);
        inf.u[0] = (g == 0) ? zp01 : ((g == 1) ? tp : 0u);
        inf.u[1] = (g == 0) ? zp23 : 0u;
        inf.u[2] = (g == 0) ? c01  : 0u;
        inf.u[3] = (g == 0) ? c23  : 0u;
    }

    // ---- L1: h1^T = W1^T @ in + b1, tanh, pack, write to hbuf
    #pragma unroll
    for (int jt = 0; jt < 8; ++jt) {
        short8 a = *(const short8*)&sm->w1f[jt][lane][0];
        f32x4 c = *(const f32x4*)&sm->b1[jt * 16 + g * 4];
        c = __builtin_amdgcn_mfma_f32_16x16x32_bf16(a, inf.s, c, 0, 0, 0);
        float h0 = fast_tanh(c[0]), h1 = fast_tanh(c[1]);
        float h2 = fast_tanh(c[2]), h3 = fast_tanh(c[3]);
        unsigned u0 = pk_bf16(h0, h1), u1 = pk_bf16(h2, h3);
        *(unsigned*)(hb + ((base_w + 32u * jt) ^ swz))      = u0;
        *(unsigned*)(hb + ((base_w + 32u * jt + 4u) ^ swz)) = u1;
    }
    asm volatile("s_waitcnt lgkmcnt(0)" ::: "memory");
    __builtin_amdgcn_sched_barrier(0);

    short8 hf[4];
    #pragma unroll
    for (int kt = 0; kt < 4; ++kt)
        hf[kt] = *(const short8*)(hb + ((base_r + 64u * kt) ^ swz));

    // ---- L2: h2^T = W2^T @ h1 + b2 (W2 frags in registers)
    #pragma unroll
    for (int jt = 0; jt < 8; ++jt) {
        f32x4 c = *(const f32x4*)&sm->b2[jt * 16 + g * 4];
        #pragma unroll
        for (int kt = 0; kt < 4; ++kt) {
            U4S8 w;
            w.u[0] = w2u[jt][kt][0]; w.u[1] = w2u[jt][kt][1];
            w.u[2] = w2u[jt][kt][2]; w.u[3] = w2u[jt][kt][3];
            c = __builtin_amdgcn_mfma_f32_16x16x32_bf16(w.s, hf[kt], c, 0, 0, 0);
        }
        float h0 = fast_tanh(c[0]), h1 = fast_tanh(c[1]);
        float h2 = fast_tanh(c[2]), h3 = fast_tanh(c[3]);
        unsigned u0 = pk_bf16(h0, h1), u1 = pk_bf16(h2, h3);
        *(unsigned*)(hb + ((base_w + 32u * jt) ^ swz))      = u0;
        *(unsigned*)(hb + ((base_w + 32u * jt + 4u) ^ swz)) = u1;
    }
    asm volatile("s_waitcnt lgkmcnt(0)" ::: "memory");
    __builtin_amdgcn_sched_barrier(0);

    short8 hf2[4];
    #pragma unroll
    for (int kt = 0; kt < 4; ++kt)
        hf2[kt] = *(const short8*)(hb + ((base_r + 64u * kt) ^ swz));

    // ---- L3: k^T = W3^T @ h2 + b3 (rows 0-3 valid)
    f32x4 c3 = *(const f32x4*)&sm->b3[g * 4];
    #pragma unroll
    for (int kt = 0; kt < 4; ++kt) {
        short8 a = *(const short8*)&sm->w3f[kt][lane][0];
        c3 = __builtin_amdgcn_mfma_f32_16x16x32_bf16(a, hf2[kt], c3, 0, 0, 0);
    }
    return c3;  // k(d=reg, r) valid in group-0 lanes
}

extern "C" __global__ void __launch_bounds__(256, 2) ffjord_kernel(
    const float* __restrict__ X, const float* __restrict__ CIN,
    const float* __restrict__ W1, const float* __restrict__ B1,
    const float* __restrict__ W2, const float* __restrict__ B2,
    const float* __restrict__ W3, const float* __restrict__ B3,
    float* __restrict__ OUT)
{
    __shared__ SMem sm;
    const int tid = threadIdx.x;
    const int wid = tid >> 6, lane = tid & 63;
    const int r = lane & 15, g = lane >> 4;
    const int rowbase = blockIdx.x * 64 + wid * 16;
    const float dt = 0.125f;

    f32x4 z = {0.f, 0.f, 0.f, 0.f};
    unsigned c01 = 0u, c23 = 0u;
    if (g == 0) {
        float4 xv = reinterpret_cast<const float4*>(X)[rowbase + r];
        z[0] = xv.x; z[1] = xv.y; z[2] = xv.z; z[3] = xv.w;
        float4 cv = reinterpret_cast<const float4*>(CIN)[rowbase + r];
        c01 = pk_bf16(cv.x, cv.y); c23 = pk_bf16(cv.z, cv.w);
    }

    unsigned w2u[8][4][4];

    for (int bij = 0; bij < NBIJ; ++bij) {
        __syncthreads();   // prior-bijector LDS use done before restaging
        // ---- stage W1^T A-frags (512 entries of 16B)
        for (int e2 = tid; e2 < 512; e2 += 256) {
            int jt = e2 >> 6, ln = e2 & 63, g2 = ln >> 4, r2 = ln & 15;
            int j = jt * 16 + r2;
            unsigned uu[4];
            #pragma unroll
            for (int ep = 0; ep < 4; ++ep) {
                int k0 = g2 * 8 + 2 * ep;
                float a = (k0 < 9)     ? W1[(bij * 9 + k0) * 128 + j]     : 0.f;
                float b = (k0 + 1 < 9) ? W1[(bij * 9 + k0 + 1) * 128 + j] : 0.f;
                uu[ep] = pk_bf16(a, b);
            }
            *(uint4*)&sm.w1f[jt][ln][0] = make_uint4(uu[0], uu[1], uu[2], uu[3]);
        }
        // ---- stage W3^T A-frags (256 entries)
        {
            int kt = tid >> 6, ln = tid & 63, g2 = ln >> 4, d = ln & 15;
            unsigned uu[4];
            #pragma unroll
            for (int ep = 0; ep < 4; ++ep) {
                int k0 = kt * 32 + g2 * 8 + 2 * ep;
                float a = (d < 4) ? W3[(bij * 128 + k0) * 4 + d]     : 0.f;
                float b = (d < 4) ? W3[(bij * 128 + k0 + 1) * 4 + d] : 0.f;
                uu[ep] = pk_bf16(a, b);
            }
            *(uint4*)&sm.w3f[kt][ln][0] = make_uint4(uu[0], uu[1], uu[2], uu[3]);
        }
        if (tid < 128) { sm.b1[tid] = B1[bij * 128 + tid];
                         sm.b2[tid] = B2[bij * 128 + tid]; }
        if (tid < 16)  sm.b3[tid] = (tid < 4) ? B3[bij * 4 + tid] : 0.f;
        __syncthreads();

        // ---- W2^T A-frags into registers (128 VGPRs, persistent per bijector)
        #pragma unroll
        for (int jt = 0; jt < 8; ++jt)
            #pragma unroll
            for (int kt = 0; kt < 4; ++kt)
                #pragma unroll
                for (int ep = 0; ep < 4; ++ep) {
                    int k0 = kt * 32 + g * 8 + 2 * ep;
                    int j = jt * 16 + r;
                    w2u[jt][kt][ep] = pk_bf16(W2[(bij * 128 + k0) * 128 + j],
                                              W2[(bij * 128 + k0 + 1) * 128 + j]);
                }

        // ---- initial k1 = f(0, z)
        f32x4 kf = mlp_eval(z, 0.0f, c01, c23, w2u, &sm, wid, lane);
        if (g == 0) sm.ks[wid][0][r] = kf;

        for (int s = 0; s < NSTEP; ++s) {
            float t0 = s * dt;
            bool last = (s == NSTEP - 1);
            for (int st = 1; st <= 6; ++st) {
                f32x4 y = z;
                for (int j = 0; j < st; ++j) {
                    float a = dt * AC[st][j];
                    f32x4 kj = sm.ks[wid][j][r];
                    y += a * kj;
                }
                if (st == 6) { z = y; if (last) break; }  // FSAL: y IS z_next
                float tt = fmaf(CN[st], dt, t0);
                f32x4 kn = mlp_eval(y, tt, c01, c23, w2u, &sm, wid, lane);
                int di = (st == 6) ? 0 : st;              // FSAL: k7 -> next k1
                if (g == 0) sm.ks[wid][di][r] = kn;
            }
        }
    }

    if (g == 0) {
        float4 o; o.x = z[0]; o.y = z[1]; o.z = z[2]; o.w = z[3];
        reinterpret_cast<float4*>(OUT)[rowbase + r] = o;
    }
}

extern "C" void kernel_launch(void* const* d_in, const int* in_sizes, int n_in,
                              void* d_out, int out_size, void* d_ws, size_t ws_size,
                              hipStream_t stream) {
    const float* X  = (const float*)d_in[0];
    const float* CI = (const float*)d_in[1];
    const float* W1 = (const float*)d_in[2];
    const float* B1 = (const float*)d_in[3];
    const float* W2 = (const float*)d_in[4];
    const float* B2 = (const float*)d_in[5];
    const float* W3 = (const float*)d_in[6];
    const float* B3 = (const float*)d_in[7];
    float* OUT = (float*)d_out;

    int btot = in_sizes[0] / 4;          // 262144 rows
    int grid = btot / 64;                // 64 rows per block (4 waves x 16)
    ffjord_kernel<<<grid, 256, 0, stream>>>(X, CI, W1, B1, W2, B2, W3, B3, OUT);
}

// Round 3
// 3330.824 us; speedup vs baseline: 12.2873x; 1.2149x over previous
//
#include <hip/hip_runtime.h>
#include <hip/hip_bf16.h>

// FFJORD: 3 bijectors x 8 DOPRI5 steps (FSAL -> 144 MLP evals total).
// MLP: [z(4), cond(4), t(1)] ->128 ->128 ->4, tanh,tanh,linear.
//
// R3 design ("phi-trick", zero shuffle):
//  - transposed MFMA scheme (batch = lane&15 in both B- and C-frags).
//  - k-index permutation phi(kt,g,e) = 32kt+16(e>>2)+4g+(e&3) chosen so each
//    lane's L2/L3 B-frag is the CONCATENATION OF ITS OWN cvt_pk'd C-frag words:
//    the inter-layer transpose costs zero instructions, zero LDS, zero barriers.
//    (Any bijective k-map is valid if A and B staging agree - same argument
//    that made R2 correct.)
//  - W2 A-frags persistent in 128 VGPRs; W1/W3 A-frags + biases in LDS
//    (broadcast reads, conflict-free). No hbuf, no asm waits -> short live
//    ranges, no spills expected.
//  - tanh = (5,4) Pade of the tanh continued fraction, clamp +-3.4, max abs
//    err ~1.4e-3 (< bf16 noise): x(945+105x^2+x^4)/(945+420x^2+15x^4),
//    with ONE v_rcp per PAIR via batched reciprocal; f32x2 math for v_pk_*.
//  - bf16 packing: v_cvt_pk_bf16_f32 (1 instr per pair).

#define NBIJ 3
#define NSTEP 8

typedef float f32x4 __attribute__((ext_vector_type(4)));
typedef float f32x2 __attribute__((ext_vector_type(2)));
typedef short short8 __attribute__((ext_vector_type(8)));
typedef unsigned u32x4 __attribute__((ext_vector_type(4)));

union U4S8 { u32x4 u; short8 s; };

__device__ static const float AC[7][6] = {
    {0.f, 0.f, 0.f, 0.f, 0.f, 0.f},
    {0.2f, 0.f, 0.f, 0.f, 0.f, 0.f},
    {0.075f, 0.225f, 0.f, 0.f, 0.f, 0.f},
    {(float)(44.0/45.0), (float)(-56.0/15.0), (float)(32.0/9.0), 0.f, 0.f, 0.f},
    {(float)(19372.0/6561.0), (float)(-25360.0/2187.0), (float)(64448.0/6561.0),
     (float)(-212.0/729.0), 0.f, 0.f},
    {(float)(9017.0/3168.0), (float)(-355.0/33.0), (float)(46732.0/5247.0),
     (float)(49.0/176.0), (float)(-5103.0/18656.0), 0.f},
    {(float)(35.0/384.0), 0.0f, (float)(500.0/1113.0), (float)(125.0/192.0),
     (float)(-2187.0/6784.0), (float)(11.0/84.0)},
};
__device__ static const float CN[7] = {
    0.0f, 0.2f, 0.3f, 0.8f, (float)(8.0/9.0), 1.0f, 1.0f
};

__device__ __forceinline__ unsigned short bf16_bits(float a) {
    union { __hip_bfloat16 h; unsigned short u; } v;
    v.h = __float2bfloat16(a);   // RNE (cold path / staging only)
    return v.u;
}
__device__ __forceinline__ unsigned pk_manual(float a, float b) {
    return (unsigned)bf16_bits(a) | ((unsigned)bf16_bits(b) << 16);
}
__device__ __forceinline__ unsigned cvt_pk(float lo, float hi) {
    unsigned r;
    asm("v_cvt_pk_bf16_f32 %0, %1, %2" : "=v"(r) : "v"(lo), "v"(hi));
    return r;   // lo -> [15:0], hi -> [31:16]
}

// tanh pair: (5,4) Pade, clamp +-3.4, one v_rcp per pair (batched reciprocal).
__device__ __forceinline__ f32x2 tanh2(float a, float b) {
    float x0 = __builtin_amdgcn_fmed3f(a, -3.4f, 3.4f);
    float x1 = __builtin_amdgcn_fmed3f(b, -3.4f, 3.4f);
    f32x2 xc = {x0, x1};
    f32x2 x2 = xc * xc;
    f32x2 num = x2 + 105.0f;
    num = x2 * num + 945.0f;          // x^4 + 105x^2 + 945
    num = xc * num;
    f32x2 den = x2 * 15.0f + 420.0f;
    den = x2 * den + 945.0f;          // 15x^4 + 420x^2 + 945
    float m = den[0] * den[1];
    float rr = __builtin_amdgcn_rcpf(m);
    f32x2 rv = { rr * den[1], rr * den[0] };
    return num * rv;
}

struct SMem {
    alignas(16) short w1f[8][64][8];   // W1^T A-frags (k = g*8+e map)   8 KB
    alignas(16) short w3f[4][64][8];   // W3^T A-frags (phi map)         4 KB
    alignas(16) float b1[128];
    alignas(16) float b2[128];
    alignas(16) float b3[16];          // zero-padded past 4
    alignas(16) f32x4 ks[4][7][16];    // [wid][stage][r]                7 KB
};

__device__ __forceinline__ f32x4 mlp_eval(
    const f32x4 y, float t, unsigned c01, unsigned c23,
    const u32x4 (&w2r)[8][4], const SMem* sm, int wid, int lane)
{
    const int r = lane & 15, g = lane >> 4;

    // ---- input B-frag (k = g*8+e): g0 = [z0..z3,c0..c3], g1 = [t,0,...]
    U4S8 inf;
    {
        unsigned zp01 = cvt_pk(y[0], y[1]);
        unsigned zp23 = cvt_pk(y[2], y[3]);
        unsigned tp   = cvt_pk(t, 0.0f);
        inf.u[0] = (g == 0) ? zp01 : ((g == 1) ? tp : 0u);
        inf.u[1] = (g == 0) ? zp23 : 0u;
        inf.u[2] = (g == 0) ? c01  : 0u;
        inf.u[3] = (g == 0) ? c23  : 0u;
    }

    const f32x4* b1p = (const f32x4*)&sm->b1[g * 4];   // +jt*4 -> imm offset
    const f32x4* b2p = (const f32x4*)&sm->b2[g * 4];
    const short8* w1p = (const short8*)&sm->w1f[0][lane][0];  // +jt*64
    const short8* w3p = (const short8*)&sm->w3f[0][lane][0];  // +kt*64

    // ---- L1: 8 MFMA; tanh+pack straight into L2 B-frags (phi layout)
    u32x4 hf[4];
    #pragma unroll
    for (int jt = 0; jt < 8; ++jt) {
        U4S8 a; a.s = w1p[jt * 64];
        f32x4 c = b1p[jt * 4];
        c = __builtin_amdgcn_mfma_f32_16x16x32_bf16(a.s, inf.s, c, 0, 0, 0);
        f32x2 tA = tanh2(c[0], c[1]);
        f32x2 tB = tanh2(c[2], c[3]);
        hf[jt >> 1][(jt & 1) * 2 + 0] = cvt_pk(tA[0], tA[1]);
        hf[jt >> 1][(jt & 1) * 2 + 1] = cvt_pk(tB[0], tB[1]);
    }

    // ---- L2: 32 MFMA (A in regs), tanh+pack into L3 B-frags (phi layout)
    u32x4 hf2[4];
    #pragma unroll
    for (int jt = 0; jt < 8; ++jt) {
        f32x4 c = b2p[jt * 4];
        #pragma unroll
        for (int kt = 0; kt < 4; ++kt) {
            U4S8 w; w.u = w2r[jt][kt];
            U4S8 bb; bb.u = hf[kt];
            c = __builtin_amdgcn_mfma_f32_16x16x32_bf16(w.s, bb.s, c, 0, 0, 0);
        }
        f32x2 tA = tanh2(c[0], c[1]);
        f32x2 tB = tanh2(c[2], c[3]);
        hf2[jt >> 1][(jt & 1) * 2 + 0] = cvt_pk(tA[0], tA[1]);
        hf2[jt >> 1][(jt & 1) * 2 + 1] = cvt_pk(tB[0], tB[1]);
    }

    // ---- L3: 4 MFMA
    f32x4 c3 = *(const f32x4*)&sm->b3[g * 4];
    #pragma unroll
    for (int kt = 0; kt < 4; ++kt) {
        U4S8 a; a.s = w3p[kt * 64];
        U4S8 bb; bb.u = hf2[kt];
        c3 = __builtin_amdgcn_mfma_f32_16x16x32_bf16(a.s, bb.s, c3, 0, 0, 0);
    }
    return c3;   // rows: feature d = g*4+reg (valid g0, d<4); col = batch r
}

extern "C" __global__ void __launch_bounds__(256, 2) ffjord_kernel(
    const float* __restrict__ X, const float* __restrict__ CIN,
    const float* __restrict__ W1, const float* __restrict__ B1,
    const float* __restrict__ W2, const float* __restrict__ B2,
    const float* __restrict__ W3, const float* __restrict__ B3,
    float* __restrict__ OUT)
{
    __shared__ SMem sm;
    const int tid = threadIdx.x;
    const int wid = tid >> 6, lane = tid & 63;
    const int r = lane & 15, g = lane >> 4;
    const int rowbase = blockIdx.x * 64 + wid * 16;
    const float dt = 0.125f;

    f32x4 z = {0.f, 0.f, 0.f, 0.f};
    unsigned c01 = 0u, c23 = 0u;
    if (g == 0) {
        float4 xv = reinterpret_cast<const float4*>(X)[rowbase + r];
        z[0] = xv.x; z[1] = xv.y; z[2] = xv.z; z[3] = xv.w;
        float4 cv = reinterpret_cast<const float4*>(CIN)[rowbase + r];
        c01 = pk_manual(cv.x, cv.y); c23 = pk_manual(cv.z, cv.w);
    }

    u32x4 w2r[8][4];

    for (int bij = 0; bij < NBIJ; ++bij) {
        __syncthreads();   // prior-bijector LDS reads done before restaging

        // ---- stage W1^T A-frags (k = g*8+e; rows k>=9 zero)
        for (int e2 = tid; e2 < 512; e2 += 256) {
            int jt = e2 >> 6, ln = e2 & 63, g2 = ln >> 4, r2 = ln & 15;
            int j = jt * 16 + r2;
            unsigned uu[4];
            #pragma unroll
            for (int ep = 0; ep < 4; ++ep) {
                int k0 = g2 * 8 + 2 * ep;
                float a = (k0 < 9)     ? W1[(bij * 9 + k0) * 128 + j]     : 0.f;
                float b = (k0 + 1 < 9) ? W1[(bij * 9 + k0 + 1) * 128 + j] : 0.f;
                uu[ep] = pk_manual(a, b);
            }
            *(uint4*)&sm.w1f[jt][ln][0] = make_uint4(uu[0], uu[1], uu[2], uu[3]);
        }
        // ---- stage W3^T A-frags with phi map: f0 = 32kt+16*(ep>>1)+4g+(ep&1)*2
        {
            int kt = tid >> 6, ln = tid & 63, g2 = ln >> 4, d = ln & 15;
            unsigned uu[4];
            #pragma unroll
            for (int ep = 0; ep < 4; ++ep) {
                int f0 = 32 * kt + 16 * (ep >> 1) + 4 * g2 + (ep & 1) * 2;
                float a = (d < 4) ? W3[(bij * 128 + f0) * 4 + d]     : 0.f;
                float b = (d < 4) ? W3[(bij * 128 + f0 + 1) * 4 + d] : 0.f;
                uu[ep] = pk_manual(a, b);
            }
            *(uint4*)&sm.w3f[kt][ln][0] = make_uint4(uu[0], uu[1], uu[2], uu[3]);
        }
        if (tid < 128) { sm.b1[tid] = B1[bij * 128 + tid];
                         sm.b2[tid] = B2[bij * 128 + tid]; }
        if (tid < 16)  sm.b3[tid] = (tid < 4) ? B3[bij * 4 + tid] : 0.f;
        __syncthreads();

        // ---- W2^T A-frags into registers (phi map), 128 VGPRs
        #pragma unroll
        for (int jt = 0; jt < 8; ++jt)
            #pragma unroll
            for (int kt = 0; kt < 4; ++kt) {
                u32x4 w;
                #pragma unroll
                for (int ep = 0; ep < 4; ++ep) {
                    int f0 = 32 * kt + 16 * (ep >> 1) + 4 * g + (ep & 1) * 2;
                    int j = jt * 16 + r;
                    w[ep] = pk_manual(W2[(bij * 128 + f0) * 128 + j],
                                      W2[(bij * 128 + f0 + 1) * 128 + j]);
                }
                w2r[jt][kt] = w;
            }

        // ---- initial k1 = f(0, z)
        f32x4 kf = mlp_eval(z, 0.0f, c01, c23, w2r, &sm, wid, lane);
        if (g == 0) sm.ks[wid][0][r] = kf;

        for (int s = 0; s < NSTEP; ++s) {
            float t0 = s * dt;
            bool last = (s == NSTEP - 1);
            for (int st = 1; st <= 6; ++st) {
                f32x4 y = z;
                for (int j = 0; j < st; ++j) {
                    float a = dt * AC[st][j];
                    f32x4 kj = sm.ks[wid][j][r];
                    y += a * kj;
                }
                if (st == 6) { z = y; if (last) break; }  // FSAL: y IS z_next
                float tt = fmaf(CN[st], dt, t0);
                f32x4 kn = mlp_eval(y, tt, c01, c23, w2r, &sm, wid, lane);
                int di = (st == 6) ? 0 : st;              // FSAL: k7 -> next k1
                if (g == 0) sm.ks[wid][di][r] = kn;
            }
        }
    }

    if (g == 0) {
        float4 o; o.x = z[0]; o.y = z[1]; o.z = z[2]; o.w = z[3];
        reinterpret_cast<float4*>(OUT)[rowbase + r] = o;
    }
}

extern "C" void kernel_launch(void* const* d_in, const int* in_sizes, int n_in,
                              void* d_out, int out_size, void* d_ws, size_t ws_size,
                              hipStream_t stream) {
    const float* X  = (const float*)d_in[0];
    const float* CI = (const float*)d_in[1];
    const float* W1 = (const float*)d_in[2];
    const float* B1 = (const float*)d_in[3];
    const float* W2 = (const float*)d_in[4];
    const float* B2 = (const float*)d_in[5];
    const float* W3 = (const float*)d_in[6];
    const float* B3 = (const float*)d_in[7];
    float* OUT = (float*)d_out;

    int btot = in_sizes[0] / 4;          // 262144 rows
    int grid = btot / 64;                // 64 rows per block (4 waves x 16)
    ffjord_kernel<<<grid, 256, 0, stream>>>(X, CI, W1, B1, W2, B2, W3, B3, OUT);
}